// Round 8
// baseline (487.977 us; speedup 1.0000x reference)
//
#include <hip/hip_runtime.h>

// ---------------------------------------------------------------------------
// Face detection pipeline, all fp32 (no fp32 MFMA on CDNA4 -> vector ALU).
// Round 7 (resubmit; infra timeout): kill the per-ci weight s_load stall —
// stage block's weight chunk in LDS (broadcast reads), hoist all 27 input
// taps before FMA section, unroll ci x2. Grids/buffers identical to round 6.
// ---------------------------------------------------------------------------

constexpr int KTOP  = 100;
constexpr int NANCH = 12288;   // 64*64*3

// ---------------- generic 3x3 SAME conv, PXT output px per thread ----------
// STRIDE==2: PXT==4, pad (0,1).  STRIDE==1: PXT==1, pad (1,1).
// FUSEOUT=true: out[co*NPX+px] = relu(acc+bias)
// FUSEOUT=false: out[(blockIdx.z*CO+co)*NPX+px] = raw partial
template<int CIN, int HIN, int WIN, int STRIDE, int PXT, int COB, int CICHUNK, bool FUSEOUT>
__global__ __launch_bounds__(256)
void convk(const float* __restrict__ in, const float* __restrict__ w,
           const float* __restrict__ bias, float* __restrict__ out, int CO)
{
    constexpr int HOUT = (STRIDE == 2) ? HIN / 2 : HIN;
    constexpr int WOUT = (STRIDE == 2) ? WIN / 2 : WIN;
    constexpr int NPX  = HOUT * WOUT;
    constexpr int GPR  = WOUT / PXT;                 // pixel-groups per row
    constexpr int NCOL = (STRIDE == 2) ? 2 * PXT + 1 : PXT + 2;
    constexpr int NW   = COB * CICHUNK * 9;

    __shared__ float lw[NW];

    const int g   = blockIdx.x * 256 + threadIdx.x;  // pixel-group id
    const int oy  = g / GPR;
    const int oxb = (g - oy * GPR) * PXT;
    const int co0 = blockIdx.y * COB;
    const int ci0 = blockIdx.z * CICHUNK;

    // stage weights for this (co-block, ci-chunk) into LDS, coalesced per-co stripe
    for (int idx = threadIdx.x; idx < NW; idx += 256) {
        const int co = idx / (CICHUNK * 9);
        const int r  = idx - co * (CICHUNK * 9);
        lw[idx] = w[((size_t)(co0 + co) * CIN + ci0) * 9 + r];
    }
    __syncthreads();

    float acc[COB][PXT];
#pragma unroll
    for (int c = 0; c < COB; ++c)
#pragma unroll
        for (int p = 0; p < PXT; ++p) acc[c][p] = 0.f;

    const int iy0 = oy * STRIDE - ((STRIDE == 1) ? 1 : 0);
    const int ixb = oxb * STRIDE - ((STRIDE == 1) ? 1 : 0);

#pragma unroll 2
    for (int cii = 0; cii < CICHUNK; ++cii) {
        const int ci = ci0 + cii;
        // ---- hoist all 3 rows of input taps into registers (batched loads)
        float cbuf[3][NCOL];
#pragma unroll
        for (int ky = 0; ky < 3; ++ky) {
            const int iy = iy0 + ky;
            const float* __restrict__ rp = in + ((size_t)ci * HIN + iy) * WIN;
            if (iy >= 0 && iy < HIN) {
                if constexpr (STRIDE == 2) {
                    const float4 q0 = *reinterpret_cast<const float4*>(rp + ixb);
                    const float4 q1 = *reinterpret_cast<const float4*>(rp + ixb + 4);
                    cbuf[ky][0] = q0.x; cbuf[ky][1] = q0.y; cbuf[ky][2] = q0.z; cbuf[ky][3] = q0.w;
                    cbuf[ky][4] = q1.x; cbuf[ky][5] = q1.y; cbuf[ky][6] = q1.z; cbuf[ky][7] = q1.w;
                    cbuf[ky][8] = (ixb + 8 < WIN) ? rp[ixb + 8] : 0.f;
                } else {
                    cbuf[ky][0] = (ixb >= 0) ? rp[ixb] : 0.f;
                    cbuf[ky][1] = rp[ixb + 1];
                    cbuf[ky][2] = (ixb + 2 < WIN) ? rp[ixb + 2] : 0.f;
                }
            } else {
#pragma unroll
                for (int k = 0; k < NCOL; ++k) cbuf[ky][k] = 0.f;
            }
        }
        // ---- FMA section; weights from LDS (wave-uniform -> broadcast)
#pragma unroll
        for (int co = 0; co < COB; ++co) {
            const float* __restrict__ wp = &lw[(co * CICHUNK + cii) * 9];
#pragma unroll
            for (int ky = 0; ky < 3; ++ky) {
#pragma unroll
                for (int kx = 0; kx < 3; ++kx) {
                    const float wv = wp[ky * 3 + kx];
#pragma unroll
                    for (int p = 0; p < PXT; ++p)
                        acc[co][p] = fmaf(cbuf[ky][STRIDE * p + kx], wv, acc[co][p]);
                }
            }
        }
    }

    const int obase = oy * WOUT + oxb;
#pragma unroll
    for (int co = 0; co < COB; ++co) {
        float r[PXT];
#pragma unroll
        for (int p = 0; p < PXT; ++p) {
            r[p] = FUSEOUT ? fmaxf(acc[co][p] + bias[co0 + co], 0.f) : acc[co][p];
        }
        float* __restrict__ op = FUSEOUT
            ? out + (size_t)(co0 + co) * NPX + obase
            : out + ((size_t)blockIdx.z * CO + co0 + co) * NPX + obase;
        if constexpr (PXT == 4) {
            float4 q; q.x = r[0]; q.y = r[1]; q.z = r[2]; q.w = r[3];
            *reinterpret_cast<float4*>(op) = q;
        } else {
#pragma unroll
            for (int p = 0; p < PXT; ++p) op[p] = r[p];
        }
    }
}

// ---------------- chunk reduction + bias (+relu) ---------------------------
template<int NCHUNK, int NPX, bool RELU>
__global__ __launch_bounds__(256)
void reducek(const float* __restrict__ part, const float* __restrict__ bias,
             float* __restrict__ out, int CO)
{
    const int t = blockIdx.x * 256 + threadIdx.x;   // < CO*NPX
    const int co = t / NPX, px = t - co * NPX;
    float s = 0.f;
#pragma unroll
    for (int c = 0; c < NCHUNK; ++c) s += part[((size_t)c * CO + co) * NPX + px];
    s += bias[co];
    out[(size_t)co * NPX + px] = RELU ? fmaxf(s, 0.f) : s;
}

// ---------------- anchor decode + sortable key -----------------------------
__global__ void decode_kernel(const float* __restrict__ head,
                              float4* __restrict__ boxes,
                              unsigned long long* __restrict__ keys)
{
    const int i = blockIdx.x * 256 + threadIdx.x;    // < 12288
    const int a = i % 3;
    const int xy = i / 3;
    const int x = xy & 63, y = xy >> 6;
    const int px = y * 64 + x;

    const float t0 = head[(a * 5 + 0) * 4096 + px];
    const float t1 = head[(a * 5 + 1) * 4096 + px];
    const float t2 = head[(a * 5 + 2) * 4096 + px];
    const float t3 = head[(a * 5 + 3) * 4096 + px];
    const float lg = head[(a * 5 + 4) * 4096 + px];

    const float sz  = (a == 0) ? 32.f : (a == 1) ? 64.f : 128.f;
    const float cxa = (x + 0.5f) * 16.f;
    const float cya = (y + 0.5f) * 16.f;

    const float cx = __fadd_rn(cxa, __fmul_rn(t0, sz));
    const float cy = __fadd_rn(cya, __fmul_rn(t1, sz));
    const float bw = __fmul_rn(sz, expf(fminf(fmaxf(t2, -4.f), 4.f)));
    const float bh = __fmul_rn(sz, expf(fminf(fmaxf(t3, -4.f), 4.f)));
    const float hw = __fmul_rn(bw, 0.5f);
    const float hh = __fmul_rn(bh, 0.5f);

    float4 bb;
    bb.x = __fsub_rn(cx, hw);
    bb.y = __fsub_rn(cy, hh);
    bb.z = __fadd_rn(cx, hw);
    bb.w = __fadd_rn(cy, hh);
    boxes[i] = bb;

    const float score = 1.f / (1.f + expf(-lg));
    unsigned long long key = 0ull;
    if (score >= 0.5f) {  // positive float bits are order-preserving
        key = ((unsigned long long)__float_as_uint(score) << 32)
            | (unsigned long long)(0xFFFFFFFFu - (unsigned)i);  // stable tiebreak
    }
    keys[i] = key;
}

// ---------------- exact rank among all keys (j-split, readlane bcast) ------
constexpr int JSPLIT = 16;
constexpr int JCHUNK = NANCH / JSPLIT;   // 768

__global__ __launch_bounds__(256)
void rank_kernel(const unsigned long long* __restrict__ keys,
                 int* __restrict__ rank)
{
    const int i = blockIdx.x * 256 + threadIdx.x;
    const unsigned long long ki = keys[i];
    const int lane = threadIdx.x & 63;
    const int jbase = blockIdx.y * JCHUNK;

    int cnt = 0;
    for (int g = 0; g < JCHUNK / 64; ++g) {
        const unsigned long long kj = keys[jbase + g * 64 + lane];
        const unsigned lo0 = (unsigned)kj;
        const unsigned hi0 = (unsigned)(kj >> 32);
#pragma unroll
        for (int l = 0; l < 64; ++l) {
            const unsigned lo = (unsigned)__builtin_amdgcn_readlane((int)lo0, l);
            const unsigned hi = (unsigned)__builtin_amdgcn_readlane((int)hi0, l);
            const unsigned long long kjj = ((unsigned long long)hi << 32) | lo;
            cnt += (kjj > ki) ? 1 : 0;
        }
    }
    if (cnt) atomicAdd(&rank[i], cnt);   // int atomics: deterministic
}

__global__ void scatter_kernel(const unsigned long long* __restrict__ keys,
                               const int* __restrict__ rank,
                               const float4* __restrict__ boxes,
                               float4* __restrict__ selb, int* __restrict__ selv)
{
    const int i = blockIdx.x * 256 + threadIdx.x;
    if (keys[i] == 0ull) return;            // below score threshold
    const int r = rank[i];
    if (r < KTOP) { selb[r] = boxes[i]; selv[r] = 1; }
}

// ---------------- sequential NMS (exact reference semantics) ---------------
__global__ __launch_bounds__(128)
void nms_kernel(const float4* __restrict__ selb, const int* __restrict__ selv,
                float4* __restrict__ drawb)
{
    __shared__ float bx1[KTOP], by1[KTOP], bx2[KTOP], by2[KTOP], ar[KTOP];
    __shared__ int kp[KTOP];
    const int t = threadIdx.x;
    if (t < KTOP) {
        const float4 b = selb[t];
        bx1[t] = b.x; by1[t] = b.y; bx2[t] = b.z; by2[t] = b.w;
        ar[t] = (b.z - b.x) * (b.w - b.y);
        kp[t] = selv[t];
    }
    __syncthreads();
    for (int i = 0; i < KTOP - 1; ++i) {
        if (t > i && t < KTOP) {
            if (kp[i] && kp[t]) {
                const float lx = fmaxf(bx1[i], bx1[t]);
                const float ly = fmaxf(by1[i], by1[t]);
                const float rx = fminf(bx2[i], bx2[t]);
                const float ry = fminf(by2[i], by2[t]);
                const float ww = fmaxf(rx - lx, 0.f);
                const float hh = fmaxf(ry - ly, 0.f);
                const float inter = ww * hh;
                const float iou = inter / (ar[i] + ar[t] - inter + 1e-9f);
                if (iou > 0.5f) kp[t] = 0;
            }
        }
        __syncthreads();
    }
    if (t < KTOP) {
        float4 d;
        if (kp[t]) {
            d.x = fminf(fmaxf(bx1[t], 0.f), 1024.f);
            d.y = fminf(fmaxf(by1[t], 0.f), 1024.f);
            d.z = fminf(fmaxf(bx2[t], 0.f), 1024.f);
            d.w = fminf(fmaxf(by2[t], 0.f), 1024.f);
        } else {  // sentinel: never matches any pixel
            d.x = 3e9f; d.y = 3e9f; d.z = -3e9f; d.w = -3e9f;
        }
        drawb[t] = d;
    }
}

// ---------------- draw red borders -----------------------------------------
__global__ __launch_bounds__(256)
void draw_kernel(const float* __restrict__ frame,
                 const float4* __restrict__ drawb, float* __restrict__ out)
{
    const int y = blockIdx.x >> 2;
    const int x = ((blockIdx.x & 3) << 8) + threadIdx.x;
    const float fy = (float)y, fx = (float)x;

    bool mask = false;
#pragma unroll 1
    for (int b = 0; b < KTOP; ++b) {
        const float4 d = drawb[b];            // wave-uniform
        if (fy >= d.y && fy < d.w) {          // scalar branch: y-row inside box?
            const bool yinner = (fy >= d.y + 4.f) && (fy < d.w - 4.f);
            const bool xin    = (fx >= d.x) && (fx < d.z);
            const bool xinner = (fx >= d.x + 4.f) && (fx < d.z - 4.f);
            mask |= xin && !(yinner && xinner);
        }
    }
    const int p = y * 1024 + x;
    const float f0 = frame[p];
    const float f1 = frame[1048576 + p];
    const float f2 = frame[2097152 + p];
    out[p]           = mask ? 1.f : f0;
    out[1048576 + p] = mask ? 0.f : f1;
    out[2097152 + p] = mask ? 0.f : f2;
}

// ---------------------------------------------------------------------------
extern "C" void kernel_launch(void* const* d_in, const int* in_sizes, int n_in,
                              void* d_out, int out_size, void* d_ws, size_t ws_size,
                              hipStream_t stream)
{
    const float* frame = (const float*)d_in[0];
    const float* w1 = (const float*)d_in[1];  const float* b1 = (const float*)d_in[2];
    const float* w2 = (const float*)d_in[3];  const float* b2 = (const float*)d_in[4];
    const float* w3 = (const float*)d_in[5];  const float* b3 = (const float*)d_in[6];
    const float* w4 = (const float*)d_in[7];  const float* b4 = (const float*)d_in[8];
    const float* wh = (const float*)d_in[9];  const float* bh = (const float*)d_in[10];

    char* ws = (char*)d_ws;
    // Region A [0, 33.55M), Region B [33.55M, 50.33M). Lifetime audit:
    //  A: buf1[0,33.55) -> part3[0,16.78) -> buf3[16.78,25.17) ->
    //     part4[0,16.78) -> buf4[25.17,29.36) -> partH[0,15.73) -> heado[29.36,29.61)
    //  B: buf2[0,16.78) -> (dead after conv3) small detect buffers
    float* buf1  = (float*)ws;
    float* buf2  = (float*)(ws + 33554432);
    float* part3 = (float*)ws;                       // 2 x 8.39M
    float* buf3  = (float*)(ws + 16777216);
    float* part4 = (float*)ws;                       // 4 x 4.19M
    float* buf4  = (float*)(ws + 25165824);
    float* partH = (float*)ws;                       // 64 x 245K = 15.73M
    float* heado = (float*)(ws + 29360128);
    char*  B     = ws + 33554432;
    float4* boxes = (float4*)(B);                                  // 196608
    unsigned long long* keys = (unsigned long long*)(B + 196608);  // 98304
    int*    rankb = (int*)(B + 294912);                            // 49152
    int*    selv  = (int*)(B + 344064);                            // 512
    float4* selb  = (float4*)(B + 344576);                         // 1600
    float4* drawb = (float4*)(B + 346176);                         // 1600
    float*  outp  = (float*)d_out;

    // backbone: 4 px/thread, LDS-staged weights, grids as round 6
    convk<3, 1024, 1024, 2, 4, 8, 3,  true ><<<dim3(256,  4, 1), 256, 0, stream>>>(frame, w1, b1, buf1, 32);
    convk<32,  512,  512, 2, 4, 4, 32, true ><<<dim3(64,  16, 1), 256, 0, stream>>>(buf1, w2, b2, buf2, 64);
    convk<64,  256,  256, 2, 4, 4, 32, false><<<dim3(16,  32, 2), 256, 0, stream>>>(buf2, w3, nullptr, part3, 128);
    reducek<2, 16384, true><<<8192, 256, 0, stream>>>(part3, b3, buf3, 128);
    convk<128, 128,  128, 2, 4, 4, 32, false><<<dim3(4,   64, 4), 256, 0, stream>>>(buf3, w4, nullptr, part4, 256);
    reducek<4, 4096, true><<<4096, 256, 0, stream>>>(part4, b4, buf4, 256);

    // head (stride1, no relu): 1 px/thread, COB=15, ci chunks of 4
    convk<256, 64, 64, 1, 1, 15, 4, false><<<dim3(16, 1, 64), 256, 0, stream>>>(buf4, wh, nullptr, partH, 15);
    reducek<64, 4096, false><<<240, 256, 0, stream>>>(partH, bh, heado, 15);

    // zero rank+selv (B small-buffer region; buf2 dead)
    hipMemsetAsync(rankb, 0, 49152 + 512, stream);

    // decode + top-100 + nms + draw
    decode_kernel<<<48, 256, 0, stream>>>(heado, boxes, keys);
    rank_kernel<<<dim3(48, JSPLIT), 256, 0, stream>>>(keys, rankb);
    scatter_kernel<<<48, 256, 0, stream>>>(keys, rankb, boxes, selb, selv);
    nms_kernel<<<1, 128, 0, stream>>>(selb, selv, drawb);
    draw_kernel<<<4096, 256, 0, stream>>>(frame, drawb, outp);
}

// Round 10
// 470.819 us; speedup vs baseline: 1.0364x; 1.0364x over previous
//
#include <hip/hip_runtime.h>

// ---------------------------------------------------------------------------
// Face detection pipeline, all fp32 (no fp32 MFMA on CDNA4 -> vector ALU).
// Round 9 (resubmit; infra timeout): revert r7 LDS-weights (VGPR 68 killed
// occupancy). Keep r6's 32-VGPR conv; raise resident waves to 8 blocks/CU:
// 2048-block grids via deeper ci-splits (conv2 x2 [ws-gated], conv3 z=4,
// conv4 z=8). Latency model: throughput = busy_cyc/wave/iter (288) x
// waves/SIMD (8) vs ~2250-cyc stall window -> VALU saturates.
// ---------------------------------------------------------------------------

constexpr int KTOP  = 100;
constexpr int NANCH = 12288;   // 64*64*3

// ---------------- generic 3x3 SAME conv, PXT output px per thread ----------
// STRIDE==2: PXT==4, pad (0,1).  STRIDE==1: PXT==1, pad (1,1).
// FUSEOUT=true: out[co*NPX+px] = relu(acc+bias)
// FUSEOUT=false: out[(blockIdx.z*CO+co)*NPX+px] = raw partial
template<int CIN, int HIN, int WIN, int STRIDE, int PXT, int COB, int CICHUNK, bool FUSEOUT>
__global__ __launch_bounds__(256)
void convk(const float* __restrict__ in, const float* __restrict__ w,
           const float* __restrict__ bias, float* __restrict__ out, int CO)
{
    constexpr int HOUT = (STRIDE == 2) ? HIN / 2 : HIN;
    constexpr int WOUT = (STRIDE == 2) ? WIN / 2 : WIN;
    constexpr int NPX  = HOUT * WOUT;
    constexpr int GPR  = WOUT / PXT;                 // pixel-groups per row
    constexpr int NCOL = (STRIDE == 2) ? 2 * PXT + 1 : PXT + 2;

    const int g   = blockIdx.x * 256 + threadIdx.x;  // pixel-group id
    const int oy  = g / GPR;
    const int oxb = (g - oy * GPR) * PXT;
    const int co0 = blockIdx.y * COB;
    const int ci0 = blockIdx.z * CICHUNK;

    float acc[COB][PXT];
#pragma unroll
    for (int c = 0; c < COB; ++c)
#pragma unroll
        for (int p = 0; p < PXT; ++p) acc[c][p] = 0.f;

    const int iy0 = oy * STRIDE - ((STRIDE == 1) ? 1 : 0);
    const int ixb = oxb * STRIDE - ((STRIDE == 1) ? 1 : 0);

#pragma unroll 2
    for (int cii = 0; cii < CICHUNK; ++cii) {
        const int ci = ci0 + cii;
#pragma unroll
        for (int ky = 0; ky < 3; ++ky) {
            const int iy = iy0 + ky;
            const float* __restrict__ rp = in + ((size_t)ci * HIN + iy) * WIN;
            float c[NCOL];
            if (iy >= 0 && iy < HIN) {
                if constexpr (STRIDE == 2) {
                    const float4 q0 = *reinterpret_cast<const float4*>(rp + ixb);
                    const float4 q1 = *reinterpret_cast<const float4*>(rp + ixb + 4);
                    c[0] = q0.x; c[1] = q0.y; c[2] = q0.z; c[3] = q0.w;
                    c[4] = q1.x; c[5] = q1.y; c[6] = q1.z; c[7] = q1.w;
                    c[8] = (ixb + 8 < WIN) ? rp[ixb + 8] : 0.f;
                } else {
                    c[0] = (ixb >= 0) ? rp[ixb] : 0.f;
                    c[1] = rp[ixb + 1];
                    c[2] = (ixb + 2 < WIN) ? rp[ixb + 2] : 0.f;
                }
            } else {
#pragma unroll
                for (int k = 0; k < NCOL; ++k) c[k] = 0.f;
            }
            // wave-uniform weight index -> s_load + SGPR-operand FMA (VGPR=32, r6)
#pragma unroll
            for (int co = 0; co < COB; ++co) {
                const float* __restrict__ wp = w + (((size_t)(co0 + co) * CIN + ci) * 3 + ky) * 3;
#pragma unroll
                for (int kx = 0; kx < 3; ++kx) {
                    const float wv = wp[kx];
#pragma unroll
                    for (int p = 0; p < PXT; ++p)
                        acc[co][p] = fmaf(c[STRIDE * p + kx], wv, acc[co][p]);
                }
            }
        }
    }

    const int obase = oy * WOUT + oxb;
#pragma unroll
    for (int co = 0; co < COB; ++co) {
        float r[PXT];
#pragma unroll
        for (int p = 0; p < PXT; ++p) {
            r[p] = FUSEOUT ? fmaxf(acc[co][p] + bias[co0 + co], 0.f) : acc[co][p];
        }
        float* __restrict__ op = FUSEOUT
            ? out + (size_t)(co0 + co) * NPX + obase
            : out + ((size_t)blockIdx.z * CO + co0 + co) * NPX + obase;
        if constexpr (PXT == 4) {
            float4 q; q.x = r[0]; q.y = r[1]; q.z = r[2]; q.w = r[3];
            *reinterpret_cast<float4*>(op) = q;
        } else {
#pragma unroll
            for (int p = 0; p < PXT; ++p) op[p] = r[p];
        }
    }
}

// ---------------- chunk reduction + bias (+relu) ---------------------------
template<int NCHUNK, int NPX, bool RELU>
__global__ __launch_bounds__(256)
void reducek(const float* __restrict__ part, const float* __restrict__ bias,
             float* __restrict__ out, int CO)
{
    const int t = blockIdx.x * 256 + threadIdx.x;   // < CO*NPX
    const int co = t / NPX, px = t - co * NPX;
    float s = 0.f;
#pragma unroll
    for (int c = 0; c < NCHUNK; ++c) s += part[((size_t)c * CO + co) * NPX + px];
    s += bias[co];
    out[(size_t)co * NPX + px] = RELU ? fmaxf(s, 0.f) : s;
}

// ---------------- anchor decode + sortable key -----------------------------
__global__ void decode_kernel(const float* __restrict__ head,
                              float4* __restrict__ boxes,
                              unsigned long long* __restrict__ keys)
{
    const int i = blockIdx.x * 256 + threadIdx.x;    // < 12288
    const int a = i % 3;
    const int xy = i / 3;
    const int x = xy & 63, y = xy >> 6;
    const int px = y * 64 + x;

    const float t0 = head[(a * 5 + 0) * 4096 + px];
    const float t1 = head[(a * 5 + 1) * 4096 + px];
    const float t2 = head[(a * 5 + 2) * 4096 + px];
    const float t3 = head[(a * 5 + 3) * 4096 + px];
    const float lg = head[(a * 5 + 4) * 4096 + px];

    const float sz  = (a == 0) ? 32.f : (a == 1) ? 64.f : 128.f;
    const float cxa = (x + 0.5f) * 16.f;
    const float cya = (y + 0.5f) * 16.f;

    const float cx = __fadd_rn(cxa, __fmul_rn(t0, sz));
    const float cy = __fadd_rn(cya, __fmul_rn(t1, sz));
    const float bw = __fmul_rn(sz, expf(fminf(fmaxf(t2, -4.f), 4.f)));
    const float bh = __fmul_rn(sz, expf(fminf(fmaxf(t3, -4.f), 4.f)));
    const float hw = __fmul_rn(bw, 0.5f);
    const float hh = __fmul_rn(bh, 0.5f);

    float4 bb;
    bb.x = __fsub_rn(cx, hw);
    bb.y = __fsub_rn(cy, hh);
    bb.z = __fadd_rn(cx, hw);
    bb.w = __fadd_rn(cy, hh);
    boxes[i] = bb;

    const float score = 1.f / (1.f + expf(-lg));
    unsigned long long key = 0ull;
    if (score >= 0.5f) {  // positive float bits are order-preserving
        key = ((unsigned long long)__float_as_uint(score) << 32)
            | (unsigned long long)(0xFFFFFFFFu - (unsigned)i);  // stable tiebreak
    }
    keys[i] = key;
}

// ---------------- exact rank among all keys (j-split, readlane bcast) ------
constexpr int JSPLIT = 16;
constexpr int JCHUNK = NANCH / JSPLIT;   // 768

__global__ __launch_bounds__(256)
void rank_kernel(const unsigned long long* __restrict__ keys,
                 int* __restrict__ rank)
{
    const int i = blockIdx.x * 256 + threadIdx.x;
    const unsigned long long ki = keys[i];
    const int lane = threadIdx.x & 63;
    const int jbase = blockIdx.y * JCHUNK;

    int cnt = 0;
    for (int g = 0; g < JCHUNK / 64; ++g) {
        const unsigned long long kj = keys[jbase + g * 64 + lane];
        const unsigned lo0 = (unsigned)kj;
        const unsigned hi0 = (unsigned)(kj >> 32);
#pragma unroll
        for (int l = 0; l < 64; ++l) {
            const unsigned lo = (unsigned)__builtin_amdgcn_readlane((int)lo0, l);
            const unsigned hi = (unsigned)__builtin_amdgcn_readlane((int)hi0, l);
            const unsigned long long kjj = ((unsigned long long)hi << 32) | lo;
            cnt += (kjj > ki) ? 1 : 0;
        }
    }
    if (cnt) atomicAdd(&rank[i], cnt);   // int atomics: deterministic
}

__global__ void scatter_kernel(const unsigned long long* __restrict__ keys,
                               const int* __restrict__ rank,
                               const float4* __restrict__ boxes,
                               float4* __restrict__ selb, int* __restrict__ selv)
{
    const int i = blockIdx.x * 256 + threadIdx.x;
    if (keys[i] == 0ull) return;            // below score threshold
    const int r = rank[i];
    if (r < KTOP) { selb[r] = boxes[i]; selv[r] = 1; }
}

// ---------------- sequential NMS (exact reference semantics) ---------------
__global__ __launch_bounds__(128)
void nms_kernel(const float4* __restrict__ selb, const int* __restrict__ selv,
                float4* __restrict__ drawb)
{
    __shared__ float bx1[KTOP], by1[KTOP], bx2[KTOP], by2[KTOP], ar[KTOP];
    __shared__ int kp[KTOP];
    const int t = threadIdx.x;
    if (t < KTOP) {
        const float4 b = selb[t];
        bx1[t] = b.x; by1[t] = b.y; bx2[t] = b.z; by2[t] = b.w;
        ar[t] = (b.z - b.x) * (b.w - b.y);
        kp[t] = selv[t];
    }
    __syncthreads();
    for (int i = 0; i < KTOP - 1; ++i) {
        if (t > i && t < KTOP) {
            if (kp[i] && kp[t]) {
                const float lx = fmaxf(bx1[i], bx1[t]);
                const float ly = fmaxf(by1[i], by1[t]);
                const float rx = fminf(bx2[i], bx2[t]);
                const float ry = fminf(by2[i], by2[t]);
                const float ww = fmaxf(rx - lx, 0.f);
                const float hh = fmaxf(ry - ly, 0.f);
                const float inter = ww * hh;
                const float iou = inter / (ar[i] + ar[t] - inter + 1e-9f);
                if (iou > 0.5f) kp[t] = 0;
            }
        }
        __syncthreads();
    }
    if (t < KTOP) {
        float4 d;
        if (kp[t]) {
            d.x = fminf(fmaxf(bx1[t], 0.f), 1024.f);
            d.y = fminf(fmaxf(by1[t], 0.f), 1024.f);
            d.z = fminf(fmaxf(bx2[t], 0.f), 1024.f);
            d.w = fminf(fmaxf(by2[t], 0.f), 1024.f);
        } else {  // sentinel: never matches any pixel
            d.x = 3e9f; d.y = 3e9f; d.z = -3e9f; d.w = -3e9f;
        }
        drawb[t] = d;
    }
}

// ---------------- draw red borders -----------------------------------------
__global__ __launch_bounds__(256)
void draw_kernel(const float* __restrict__ frame,
                 const float4* __restrict__ drawb, float* __restrict__ out)
{
    const int y = blockIdx.x >> 2;
    const int x = ((blockIdx.x & 3) << 8) + threadIdx.x;
    const float fy = (float)y, fx = (float)x;

    bool mask = false;
#pragma unroll 1
    for (int b = 0; b < KTOP; ++b) {
        const float4 d = drawb[b];            // wave-uniform
        if (fy >= d.y && fy < d.w) {          // scalar branch: y-row inside box?
            const bool yinner = (fy >= d.y + 4.f) && (fy < d.w - 4.f);
            const bool xin    = (fx >= d.x) && (fx < d.z);
            const bool xinner = (fx >= d.x + 4.f) && (fx < d.z - 4.f);
            mask |= xin && !(yinner && xinner);
        }
    }
    const int p = y * 1024 + x;
    const float f0 = frame[p];
    const float f1 = frame[1048576 + p];
    const float f2 = frame[2097152 + p];
    out[p]           = mask ? 1.f : f0;
    out[1048576 + p] = mask ? 0.f : f1;
    out[2097152 + p] = mask ? 0.f : f2;
}

// ---------------------------------------------------------------------------
extern "C" void kernel_launch(void* const* d_in, const int* in_sizes, int n_in,
                              void* d_out, int out_size, void* d_ws, size_t ws_size,
                              hipStream_t stream)
{
    const float* frame = (const float*)d_in[0];
    const float* w1 = (const float*)d_in[1];  const float* b1 = (const float*)d_in[2];
    const float* w2 = (const float*)d_in[3];  const float* b2 = (const float*)d_in[4];
    const float* w3 = (const float*)d_in[5];  const float* b3 = (const float*)d_in[6];
    const float* w4 = (const float*)d_in[7];  const float* b4 = (const float*)d_in[8];
    const float* wh = (const float*)d_in[9];  const float* bh = (const float*)d_in[10];

    char* ws = (char*)d_ws;
    const bool big = ws_size >= (size_t)70 * 1024 * 1024;  // constant per session

    // ---- memory map (lifetimes audited for both paths) --------------------
    // big:      buf1[0,33.55) -> part2[33.55,67.11) -> buf2[0,16.78)
    //           -> part3[16.78,50.33) -> buf3[50.33,58.72) -> part4[0,33.55)
    //           -> buf4[33.55,37.75) -> partH[0,15.73) -> heado[46.14M)
    //           -> detect[47.19M)
    // fallback: buf1[0,33.55) -> buf2[33.55,50.33) (fused conv2)
    //           -> part3[0,33.55) -> buf3[33.55,41.94) -> part4[0,33.55)
    //           -> buf4[41.94,46.14) -> partH[0,15.73) -> heado[16.78M)
    //           -> detect[17.83M)
    float* buf1  = (float*)ws;
    float* part2 = (float*)(ws + 33554432);                       // big only
    float* buf2  = big ? (float*)ws : (float*)(ws + 33554432);
    float* part3 = big ? (float*)(ws + 16777216) : (float*)ws;
    float* buf3  = big ? (float*)(ws + 50331648) : (float*)(ws + 33554432);
    float* part4 = (float*)ws;
    float* buf4  = big ? (float*)(ws + 33554432) : (float*)(ws + 41943040);
    float* partH = (float*)ws;
    float* heado = big ? (float*)(ws + 46137344) : (float*)(ws + 16777216);
    char*  D     = big ? (ws + 47185920) : (ws + 17825792);
    float4* boxes = (float4*)(D);                                  // 196608
    unsigned long long* keys = (unsigned long long*)(D + 196608);  // 98304
    int*    rankb = (int*)(D + 294912);                            // 49152
    int*    selv  = (int*)(D + 344064);                            // 512
    float4* selb  = (float4*)(D + 344576);                         // 1600
    float4* drawb = (float4*)(D + 346176);                         // 1600
    float*  outp  = (float*)d_out;

    // ---- backbone: 2048-block grids (8 blocks/CU, 32 waves/CU) ------------
    convk<3, 1024, 1024, 2, 4, 2, 3, true ><<<dim3(256, 16, 1), 256, 0, stream>>>(frame, w1, b1, buf1, 32);

    if (big) {  // conv2 ci-split x2 -> 2048 blocks
        convk<32, 512, 512, 2, 4, 4, 16, false><<<dim3(64, 16, 2), 256, 0, stream>>>(buf1, w2, nullptr, part2, 64);
        reducek<2, 65536, true><<<16384, 256, 0, stream>>>(part2, b2, buf2, 64);
    } else {    // fallback: fused conv2, 1024 blocks (r6 behavior)
        convk<32, 512, 512, 2, 4, 4, 32, true ><<<dim3(64, 16, 1), 256, 0, stream>>>(buf1, w2, b2, buf2, 64);
    }

    convk<64, 256, 256, 2, 4, 4, 16, false><<<dim3(16, 32, 4), 256, 0, stream>>>(buf2, w3, nullptr, part3, 128);
    reducek<4, 16384, true><<<8192, 256, 0, stream>>>(part3, b3, buf3, 128);

    convk<128, 128, 128, 2, 4, 4, 16, false><<<dim3(4, 64, 8), 256, 0, stream>>>(buf3, w4, nullptr, part4, 256);
    reducek<8, 4096, true><<<4096, 256, 0, stream>>>(part4, b4, buf4, 256);

    // head (stride1, no relu): 1 px/thread, COB=15, ci chunks of 4
    convk<256, 64, 64, 1, 1, 15, 4, false><<<dim3(16, 1, 64), 256, 0, stream>>>(buf4, wh, nullptr, partH, 15);
    reducek<64, 4096, false><<<240, 256, 0, stream>>>(partH, bh, heado, 15);

    // zero rank+selv
    hipMemsetAsync(rankb, 0, 49152 + 512, stream);

    // decode + top-100 + nms + draw
    decode_kernel<<<48, 256, 0, stream>>>(heado, boxes, keys);
    rank_kernel<<<dim3(48, JSPLIT), 256, 0, stream>>>(keys, rankb);
    scatter_kernel<<<48, 256, 0, stream>>>(keys, rankb, boxes, selb, selv);
    nms_kernel<<<1, 128, 0, stream>>>(selb, selv, drawb);
    draw_kernel<<<4096, 256, 0, stream>>>(frame, drawb, outp);
}

// Round 11
// 403.651 us; speedup vs baseline: 1.2089x; 1.1664x over previous
//
#include <hip/hip_runtime.h>

// ---------------------------------------------------------------------------
// Face detection pipeline, all fp32 (no fp32 MFMA on CDNA4 -> vector ALU).
// Round 11: fix L1-tag (TA) saturation. r10 showed adding waves doesn't help
// (75.8us both at 1024 and 2048 blocks, VALU ~40%): waves stall together on
// the shared L1 pipe. Old layout: PXT=4 -> inter-lane stride 32B -> ~16 lines
// per load instr at 50% efficiency. New: PXT=1, wave = 64 contiguous ox ->
// taps are stride-8B float2 + scalar (4 lines/instr, 100% eff) -> TA ~6x
// cheaper. COB=8 keeps FMA density & halves co-block input re-reads.
// Branchless boundaries (clamped addr + select). Accum order (ci,ky,kx) == r6.
// ---------------------------------------------------------------------------

constexpr int KTOP  = 100;
constexpr int NANCH = 12288;   // 64*64*3

// ---------------- generic 3x3 SAME conv, 1 output px per lane --------------
// wave = 64 consecutive ox in one output row. STRIDE==2: pad (0,1);
// STRIDE==1: pad (1,1).
// FUSEOUT=true: out[co*NPX+px] = relu(acc+bias)
// FUSEOUT=false: out[(blockIdx.z*CO+co)*NPX+px] = raw partial
template<int CIN, int HIN, int WIN, int STRIDE, int COB, int CICHUNK, bool FUSEOUT>
__global__ __launch_bounds__(256)
void convk(const float* __restrict__ in, const float* __restrict__ w,
           const float* __restrict__ bias, float* __restrict__ out, int CO)
{
    constexpr int HOUT = (STRIDE == 2) ? HIN / 2 : HIN;
    constexpr int WOUT = (STRIDE == 2) ? WIN / 2 : WIN;
    constexpr int NPX  = HOUT * WOUT;
    constexpr int SPR  = WOUT / 64;                  // 64-px segments per row

    const int lane = threadIdx.x & 63;
    const int seg  = blockIdx.x * 4 + (threadIdx.x >> 6);
    const int oy   = seg / SPR;
    const int ox   = (seg - oy * SPR) * 64 + lane;
    const int co0  = blockIdx.y * COB;
    const int ci0  = blockIdx.z * CICHUNK;

    float acc[COB];
#pragma unroll
    for (int c = 0; c < COB; ++c) acc[c] = 0.f;

    // ---- loop-invariant row offsets (clamped) + validity masks ------------
    size_t ro[3];
    bool   rm[3];
#pragma unroll
    for (int ky = 0; ky < 3; ++ky) {
        const int iy = (STRIDE == 2) ? (2 * oy + ky) : (oy + ky - 1);
        rm[ky] = (iy >= 0) && (iy < HIN);
        const int iyc = iy < 0 ? 0 : (iy > HIN - 1 ? HIN - 1 : iy);
        ro[ky] = (size_t)iyc * WIN;
    }
    // ---- loop-invariant column offsets (clamped) + masks ------------------
    int  xa, xb, xc;
    bool ma, mc;
    if constexpr (STRIDE == 2) {
        xa = 2 * ox;                                  // float2 -> taps kx=0,1
        xb = 0;                                       // unused
        mc = (2 * ox + 2) < WIN;
        xc = mc ? 2 * ox + 2 : WIN - 1;
        ma = true;
    } else {
        ma = ox > 0;
        xa = ma ? ox - 1 : 0;
        xb = ox;
        mc = ox < WIN - 1;
        xc = mc ? ox + 1 : WIN - 1;
    }

    for (int cii = 0; cii < CICHUNK; ++cii) {
        const int ci = ci0 + cii;
        const float* __restrict__ cp = in + (size_t)ci * (HIN * WIN);
#pragma unroll
        for (int ky = 0; ky < 3; ++ky) {
            float t0, t1, t2;
            if constexpr (STRIDE == 2) {
                const float2 p = *reinterpret_cast<const float2*>(cp + ro[ky] + xa);
                const float  e = cp[ro[ky] + xc];
                t0 = rm[ky] ? p.x : 0.f;
                t1 = rm[ky] ? p.y : 0.f;
                t2 = (rm[ky] && mc) ? e : 0.f;
            } else {
                const float a = cp[ro[ky] + xa];
                const float b = cp[ro[ky] + xb];
                const float e = cp[ro[ky] + xc];
                t0 = (rm[ky] && ma) ? a : 0.f;
                t1 = rm[ky] ? b : 0.f;
                t2 = (rm[ky] && mc) ? e : 0.f;
            }
            // wave-uniform weight address -> s_load + SGPR-operand FMA
#pragma unroll
            for (int co = 0; co < COB; ++co) {
                const float* __restrict__ wp =
                    w + (((size_t)(co0 + co) * CIN + ci) * 3 + ky) * 3;
                acc[co] = fmaf(t0, wp[0], acc[co]);
                acc[co] = fmaf(t1, wp[1], acc[co]);
                acc[co] = fmaf(t2, wp[2], acc[co]);
            }
        }
    }

    const int op = oy * WOUT + ox;
#pragma unroll
    for (int co = 0; co < COB; ++co) {
        if constexpr (FUSEOUT) {
            out[(size_t)(co0 + co) * NPX + op] =
                fmaxf(acc[co] + bias[co0 + co], 0.f);
        } else {
            out[((size_t)blockIdx.z * CO + co0 + co) * NPX + op] = acc[co];
        }
    }
}

// ---------------- chunk reduction + bias (+relu) ---------------------------
template<int NCHUNK, int NPX, bool RELU>
__global__ __launch_bounds__(256)
void reducek(const float* __restrict__ part, const float* __restrict__ bias,
             float* __restrict__ out, int CO)
{
    const int t = blockIdx.x * 256 + threadIdx.x;   // < CO*NPX
    const int co = t / NPX, px = t - co * NPX;
    float s = 0.f;
#pragma unroll
    for (int c = 0; c < NCHUNK; ++c) s += part[((size_t)c * CO + co) * NPX + px];
    s += bias[co];
    out[(size_t)co * NPX + px] = RELU ? fmaxf(s, 0.f) : s;
}

// ---------------- anchor decode + sortable key -----------------------------
__global__ void decode_kernel(const float* __restrict__ head,
                              float4* __restrict__ boxes,
                              unsigned long long* __restrict__ keys)
{
    const int i = blockIdx.x * 256 + threadIdx.x;    // < 12288
    const int a = i % 3;
    const int xy = i / 3;
    const int x = xy & 63, y = xy >> 6;
    const int px = y * 64 + x;

    const float t0 = head[(a * 5 + 0) * 4096 + px];
    const float t1 = head[(a * 5 + 1) * 4096 + px];
    const float t2 = head[(a * 5 + 2) * 4096 + px];
    const float t3 = head[(a * 5 + 3) * 4096 + px];
    const float lg = head[(a * 5 + 4) * 4096 + px];

    const float sz  = (a == 0) ? 32.f : (a == 1) ? 64.f : 128.f;
    const float cxa = (x + 0.5f) * 16.f;
    const float cya = (y + 0.5f) * 16.f;

    const float cx = __fadd_rn(cxa, __fmul_rn(t0, sz));
    const float cy = __fadd_rn(cya, __fmul_rn(t1, sz));
    const float bw = __fmul_rn(sz, expf(fminf(fmaxf(t2, -4.f), 4.f)));
    const float bh = __fmul_rn(sz, expf(fminf(fmaxf(t3, -4.f), 4.f)));
    const float hw = __fmul_rn(bw, 0.5f);
    const float hh = __fmul_rn(bh, 0.5f);

    float4 bb;
    bb.x = __fsub_rn(cx, hw);
    bb.y = __fsub_rn(cy, hh);
    bb.z = __fadd_rn(cx, hw);
    bb.w = __fadd_rn(cy, hh);
    boxes[i] = bb;

    const float score = 1.f / (1.f + expf(-lg));
    unsigned long long key = 0ull;
    if (score >= 0.5f) {  // positive float bits are order-preserving
        key = ((unsigned long long)__float_as_uint(score) << 32)
            | (unsigned long long)(0xFFFFFFFFu - (unsigned)i);  // stable tiebreak
    }
    keys[i] = key;
}

// ---------------- exact rank among all keys (j-split, readlane bcast) ------
constexpr int JSPLIT = 16;
constexpr int JCHUNK = NANCH / JSPLIT;   // 768

__global__ __launch_bounds__(256)
void rank_kernel(const unsigned long long* __restrict__ keys,
                 int* __restrict__ rank)
{
    const int i = blockIdx.x * 256 + threadIdx.x;
    const unsigned long long ki = keys[i];
    const int lane = threadIdx.x & 63;
    const int jbase = blockIdx.y * JCHUNK;

    int cnt = 0;
    for (int g = 0; g < JCHUNK / 64; ++g) {
        const unsigned long long kj = keys[jbase + g * 64 + lane];
        const unsigned lo0 = (unsigned)kj;
        const unsigned hi0 = (unsigned)(kj >> 32);
#pragma unroll
        for (int l = 0; l < 64; ++l) {
            const unsigned lo = (unsigned)__builtin_amdgcn_readlane((int)lo0, l);
            const unsigned hi = (unsigned)__builtin_amdgcn_readlane((int)hi0, l);
            const unsigned long long kjj = ((unsigned long long)hi << 32) | lo;
            cnt += (kjj > ki) ? 1 : 0;
        }
    }
    if (cnt) atomicAdd(&rank[i], cnt);   // int atomics: deterministic
}

__global__ void scatter_kernel(const unsigned long long* __restrict__ keys,
                               const int* __restrict__ rank,
                               const float4* __restrict__ boxes,
                               float4* __restrict__ selb, int* __restrict__ selv)
{
    const int i = blockIdx.x * 256 + threadIdx.x;
    if (keys[i] == 0ull) return;            // below score threshold
    const int r = rank[i];
    if (r < KTOP) { selb[r] = boxes[i]; selv[r] = 1; }
}

// ---------------- sequential NMS (exact reference semantics) ---------------
__global__ __launch_bounds__(128)
void nms_kernel(const float4* __restrict__ selb, const int* __restrict__ selv,
                float4* __restrict__ drawb)
{
    __shared__ float bx1[KTOP], by1[KTOP], bx2[KTOP], by2[KTOP], ar[KTOP];
    __shared__ int kp[KTOP];
    const int t = threadIdx.x;
    if (t < KTOP) {
        const float4 b = selb[t];
        bx1[t] = b.x; by1[t] = b.y; bx2[t] = b.z; by2[t] = b.w;
        ar[t] = (b.z - b.x) * (b.w - b.y);
        kp[t] = selv[t];
    }
    __syncthreads();
    for (int i = 0; i < KTOP - 1; ++i) {
        if (t > i && t < KTOP) {
            if (kp[i] && kp[t]) {
                const float lx = fmaxf(bx1[i], bx1[t]);
                const float ly = fmaxf(by1[i], by1[t]);
                const float rx = fminf(bx2[i], bx2[t]);
                const float ry = fminf(by2[i], by2[t]);
                const float ww = fmaxf(rx - lx, 0.f);
                const float hh = fmaxf(ry - ly, 0.f);
                const float inter = ww * hh;
                const float iou = inter / (ar[i] + ar[t] - inter + 1e-9f);
                if (iou > 0.5f) kp[t] = 0;
            }
        }
        __syncthreads();
    }
    if (t < KTOP) {
        float4 d;
        if (kp[t]) {
            d.x = fminf(fmaxf(bx1[t], 0.f), 1024.f);
            d.y = fminf(fmaxf(by1[t], 0.f), 1024.f);
            d.z = fminf(fmaxf(bx2[t], 0.f), 1024.f);
            d.w = fminf(fmaxf(by2[t], 0.f), 1024.f);
        } else {  // sentinel: never matches any pixel
            d.x = 3e9f; d.y = 3e9f; d.z = -3e9f; d.w = -3e9f;
        }
        drawb[t] = d;
    }
}

// ---------------- draw red borders -----------------------------------------
__global__ __launch_bounds__(256)
void draw_kernel(const float* __restrict__ frame,
                 const float4* __restrict__ drawb, float* __restrict__ out)
{
    const int y = blockIdx.x >> 2;
    const int x = ((blockIdx.x & 3) << 8) + threadIdx.x;
    const float fy = (float)y, fx = (float)x;

    bool mask = false;
#pragma unroll 1
    for (int b = 0; b < KTOP; ++b) {
        const float4 d = drawb[b];            // wave-uniform
        if (fy >= d.y && fy < d.w) {          // scalar branch: y-row inside box?
            const bool yinner = (fy >= d.y + 4.f) && (fy < d.w - 4.f);
            const bool xin    = (fx >= d.x) && (fx < d.z);
            const bool xinner = (fx >= d.x + 4.f) && (fx < d.z - 4.f);
            mask |= xin && !(yinner && xinner);
        }
    }
    const int p = y * 1024 + x;
    const float f0 = frame[p];
    const float f1 = frame[1048576 + p];
    const float f2 = frame[2097152 + p];
    out[p]           = mask ? 1.f : f0;
    out[1048576 + p] = mask ? 0.f : f1;
    out[2097152 + p] = mask ? 0.f : f2;
}

// ---------------------------------------------------------------------------
extern "C" void kernel_launch(void* const* d_in, const int* in_sizes, int n_in,
                              void* d_out, int out_size, void* d_ws, size_t ws_size,
                              hipStream_t stream)
{
    const float* frame = (const float*)d_in[0];
    const float* w1 = (const float*)d_in[1];  const float* b1 = (const float*)d_in[2];
    const float* w2 = (const float*)d_in[3];  const float* b2 = (const float*)d_in[4];
    const float* w3 = (const float*)d_in[5];  const float* b3 = (const float*)d_in[6];
    const float* w4 = (const float*)d_in[7];  const float* b4 = (const float*)d_in[8];
    const float* wh = (const float*)d_in[9];  const float* bh = (const float*)d_in[10];

    char* ws = (char*)d_ws;
    // ---- memory map (single path, peak 50.33M; lifetimes audited) ---------
    //  buf1 [0,33.55M) -> buf2 [33.55,50.33M) (conv2 fused, no partials)
    //  part3[0,16.78M) (buf1 dead) -> buf3 [16.78,25.17M)
    //  part4[0,16.78M) (part3 dead) -> buf4 [25.17,29.36M)
    //  partH[0,7.87M)  (part4 dead) -> heado [8.39,8.63M)
    //  D at 33.55M (buf2 dead after conv3)
    float* buf1  = (float*)ws;
    float* buf2  = (float*)(ws + 33554432);
    float* part3 = (float*)ws;
    float* buf3  = (float*)(ws + 16777216);
    float* part4 = (float*)ws;
    float* buf4  = (float*)(ws + 25165824);
    float* partH = (float*)ws;
    float* heado = (float*)(ws + 8388608);
    char*  D     = ws + 33554432;
    float4* boxes = (float4*)(D);                                  // 196608
    unsigned long long* keys = (unsigned long long*)(D + 196608);  // 98304
    int*    rankb = (int*)(D + 294912);                            // 49152
    int*    selv  = (int*)(D + 344064);                            // 512
    float4* selb  = (float4*)(D + 344576);                         // 1600
    float4* drawb = (float4*)(D + 346176);                         // 1600
    float*  outp  = (float*)d_out;

    // ---- backbone: lane-contiguous layout, COB=8 --------------------------
    convk<3,  1024, 1024, 2, 8, 3,  true ><<<dim3(1024, 4, 1), 256, 0, stream>>>(frame, w1, b1, buf1, 32);
    convk<32,  512,  512, 2, 8, 32, true ><<<dim3(256,  8, 1), 256, 0, stream>>>(buf1, w2, b2, buf2, 64);

    convk<64,  256,  256, 2, 8, 32, false><<<dim3(64, 16, 2), 256, 0, stream>>>(buf2, w3, nullptr, part3, 128);
    reducek<2, 16384, true><<<8192, 256, 0, stream>>>(part3, b3, buf3, 128);

    convk<128, 128,  128, 2, 8, 32, false><<<dim3(16, 32, 4), 256, 0, stream>>>(buf3, w4, nullptr, part4, 256);
    reducek<4, 4096, true><<<4096, 256, 0, stream>>>(part4, b4, buf4, 256);

    // head (stride1, no relu): COB=15, ci chunks of 8, z=32
    convk<256, 64, 64, 1, 15, 8, false><<<dim3(16, 1, 32), 256, 0, stream>>>(buf4, wh, nullptr, partH, 15);
    reducek<32, 4096, false><<<240, 256, 0, stream>>>(partH, bh, heado, 15);

    // zero rank+selv (D region; buf2 dead after conv3)
    hipMemsetAsync(rankb, 0, 49152 + 512, stream);

    // decode + top-100 + nms + draw
    decode_kernel<<<48, 256, 0, stream>>>(heado, boxes, keys);
    rank_kernel<<<dim3(48, JSPLIT), 256, 0, stream>>>(keys, rankb);
    scatter_kernel<<<48, 256, 0, stream>>>(keys, rankb, boxes, selb, selv);
    nms_kernel<<<1, 128, 0, stream>>>(selb, selv, drawb);
    draw_kernel<<<4096, 256, 0, stream>>>(frame, drawb, outp);
}